// Round 1
// baseline (1605.393 us; speedup 1.0000x reference)
//
#include <hip/hip_runtime.h>
#include <math.h>

#define SCALE 0.4082482904638631f   // 1/sqrt(6)

#define BATCH 8
#define CIN   48
#define HW    256
#define NPIX  65536
#define TILE  16
#define HALO  18
#define HP    324          // 18*18
#define T1    384

// workspace layout (float elements)
#define V_OFF   0
#define V_SIZE  (BATCH*48*NPIX)        // 25,165,824 floats (~100.7 MB)
#define GP_OFF  (V_OFF + V_SIZE)
#define GP_SIZE (2048*384)             // per-tile gram partials (~3.1 MB)
#define M_OFF   (GP_OFF + GP_SIZE)
#define M_SIZE  (BATCH*48*48)

// ---------------------------------------------------------------------------
// K1: fused 1x1 conv + 3x3 depthwise. Per 16x16 tile:
//   - stage x halo (18x18x48) in LDS
//   - per head h: compute 12 channels (q0..5,k0..5) on halo, dw-conv at own
//     pixel, block-reduce 48 gram values (6 qq, 6 kk, 36 q*k) -> gram_part
//   - v channels (6 groups of 8): same 2-stage conv, store to v_ws
// LDS: xs 62.2KB + qh 15.6KB + pr 0.75KB = 78.5KB -> 2 blocks/CU
// ---------------------------------------------------------------------------
__global__ __launch_bounds__(T1, 3) void k1_qkv(
    const float* __restrict__ x, const float* __restrict__ w1,
    const float* __restrict__ wd, float* __restrict__ v_ws,
    float* __restrict__ gram_part)
{
  __shared__ float xs[CIN * HP];                 // [ic][halo_pixel]
  __shared__ __align__(16) float qh[HP * 12];    // [halo_pixel][channel-slot]
  __shared__ float pr[192];

  const int blk  = blockIdx.x;       // b*256 + tile
  const int b    = blk >> 8;
  const int tile = blk & 255;
  const int ty0  = (tile >> 4) * TILE;
  const int tx0  = (tile & 15) * TILE;
  const int tid  = threadIdx.x;

  // ---- load x halo tile into LDS (zero padding outside image) ----
  const float* xb = x + (size_t)b * CIN * NPIX;
  for (int e = tid; e < CIN * HP; e += T1) {
    const int ic = e / HP;
    const int hp = e - ic * HP;
    const int r  = hp / HALO;
    const int c  = hp - r * HALO;
    const int gy = ty0 - 1 + r;
    const int gx = tx0 - 1 + c;
    float v = 0.0f;
    if ((unsigned)gy < (unsigned)HW && (unsigned)gx < (unsigned)HW)
      v = xb[ic * NPIX + gy * HW + gx];
    xs[e] = v;
  }
  __syncthreads();

  const int px = tid & 15;
  const int py = tid >> 4;                       // valid when tid < 256
  float* gp = gram_part + (size_t)blk * 384;

  // ================= heads: q & k channels + gram =================
  for (int h = 0; h < 8; ++h) {
    // stage 1: 1x1 conv on halo pixels for q(6h..6h+5), k(48+6h..48+6h+5)
    if (tid < HP) {
      float acc[12];
#pragma unroll
      for (int j = 0; j < 12; ++j) acc[j] = 0.0f;
      const float* wq = w1 + (6 * h) * CIN;
      const float* wk = w1 + (48 + 6 * h) * CIN;
#pragma unroll
      for (int ic = 0; ic < CIN; ++ic) {
        const float xv = xs[ic * HP + tid];
#pragma unroll
        for (int j = 0; j < 6; ++j) {
          acc[j]     = fmaf(wq[j * CIN + ic], xv, acc[j]);
          acc[6 + j] = fmaf(wk[j * CIN + ic], xv, acc[6 + j]);
        }
      }
      float4* qp = (float4*)(qh + tid * 12);
      qp[0] = make_float4(acc[0], acc[1], acc[2],  acc[3]);
      qp[1] = make_float4(acc[4], acc[5], acc[6],  acc[7]);
      qp[2] = make_float4(acc[8], acc[9], acc[10], acc[11]);
    }
    __syncthreads();

    // stage 2: 3x3 depthwise conv at own pixel
    float val[12];
    if (tid < 256) {
#pragma unroll
      for (int j = 0; j < 12; ++j) val[j] = 0.0f;
#pragma unroll
      for (int t = 0; t < 9; ++t) {
        const int dy = t / 3, dx = t - 3 * (t / 3);
        const float* base = qh + ((py + dy) * HALO + (px + dx)) * 12;
        float f[12];
        *(float4*)(f + 0) = *(const float4*)(base + 0);
        *(float4*)(f + 4) = *(const float4*)(base + 4);
        *(float4*)(f + 8) = *(const float4*)(base + 8);
        float w_[12];
#pragma unroll
        for (int j = 0; j < 6; ++j) {
          w_[j]     = wd[(6 * h + j) * 9 + t];
          w_[6 + j] = wd[(48 + 6 * h + j) * 9 + t];
        }
#pragma unroll
        for (int j = 0; j < 12; ++j) val[j] = fmaf(w_[j], f[j], val[j]);
      }
    }
    __syncthreads();   // all stage-2 reads of qh done -> safe to reuse region

    // write per-pixel q,k to (reused) qh for block-level gram reduction
    if (tid < 256) {
      float4* qp = (float4*)(qh + tid * 12);
      qp[0] = make_float4(val[0], val[1], val[2],  val[3]);
      qp[1] = make_float4(val[4], val[5], val[6],  val[7]);
      qp[2] = make_float4(val[8], val[9], val[10], val[11]);
    }
    __syncthreads();

    // reduce 48 values (6 qq, 6 kk, 36 S_de) over 256 pixels, 4 chunks of 64
    if (tid < 192) {
      const int vv = tid >> 2, ch = tid & 3;
      const float* base = qh + ch * 64 * 12;
      float s = 0.0f;
      if (vv < 12) {                      // vv<6: ||q_d||^2 ; 6..11: ||k_e||^2
        for (int p = 0; p < 64; ++p) {
          const float a = base[p * 12 + vv];
          s = fmaf(a, a, s);
        }
      } else {                            // S[d][e] = sum q_d * k_e
        const int de = vv - 12;
        const int d = de / 6, e = de - 6 * (de / 6);
        for (int p = 0; p < 64; ++p)
          s = fmaf(base[p * 12 + d], base[p * 12 + 6 + e], s);
      }
      pr[vv * 4 + ch] = s;
    }
    __syncthreads();
    if (tid < 48)
      gp[h * 48 + tid] = pr[tid * 4] + pr[tid * 4 + 1] + pr[tid * 4 + 2] + pr[tid * 4 + 3];
    __syncthreads();
  }

  // ================= v channels: 6 groups of 8 =================
  for (int g = 0; g < 6; ++g) {
    if (tid < HP) {
      float acc[8];
#pragma unroll
      for (int j = 0; j < 8; ++j) acc[j] = 0.0f;
      const float* wv = w1 + (96 + 8 * g) * CIN;
#pragma unroll
      for (int ic = 0; ic < CIN; ++ic) {
        const float xv = xs[ic * HP + tid];
#pragma unroll
        for (int j = 0; j < 8; ++j)
          acc[j] = fmaf(wv[j * CIN + ic], xv, acc[j]);
      }
      float4* qp = (float4*)(qh + tid * 12);
      qp[0] = make_float4(acc[0], acc[1], acc[2], acc[3]);
      qp[1] = make_float4(acc[4], acc[5], acc[6], acc[7]);
    }
    __syncthreads();

    if (tid < 256) {
      float val[8];
#pragma unroll
      for (int j = 0; j < 8; ++j) val[j] = 0.0f;
#pragma unroll
      for (int t = 0; t < 9; ++t) {
        const int dy = t / 3, dx = t - 3 * (t / 3);
        const float* base = qh + ((py + dy) * HALO + (px + dx)) * 12;
        float f[8];
        *(float4*)(f + 0) = *(const float4*)(base + 0);
        *(float4*)(f + 4) = *(const float4*)(base + 4);
        float w_[8];
#pragma unroll
        for (int j = 0; j < 8; ++j) w_[j] = wd[(96 + 8 * g + j) * 9 + t];
#pragma unroll
        for (int j = 0; j < 8; ++j) val[j] = fmaf(w_[j], f[j], val[j]);
      }
      const int gy = ty0 + py, gx = tx0 + px;
      float* vo = v_ws + (size_t)b * 48 * NPIX + gy * HW + gx;
#pragma unroll
      for (int j = 0; j < 8; ++j) vo[(size_t)(8 * g + j) * NPIX] = val[j];
    }
    __syncthreads();
  }
}

// ---------------------------------------------------------------------------
// K2: per (b,head): reduce tile partials -> norms + S -> softmax(attn) ->
//     M_b[:, 6h+e] = sum_d Wp[:, 6h+d] * attn[d][e]
// ---------------------------------------------------------------------------
__global__ void k2_attn(const float* __restrict__ gram_part,
                        const float* __restrict__ wp, float* __restrict__ Mmat)
{
  const int b = blockIdx.x >> 3;
  const int h = blockIdx.x & 7;
  __shared__ float S[48];
  __shared__ float attn[36];
  const int tid = threadIdx.x;   // 64 threads

  if (tid < 48) {
    const float* gpp = gram_part + (size_t)(b * 256) * 384 + h * 48 + tid;
    float s = 0.0f;
    for (int t = 0; t < 256; ++t) s += gpp[(size_t)t * 384];
    S[tid] = s;
  }
  __syncthreads();
  if (tid < 36) {
    const int d = tid / 6, e = tid - 6 * d;
    const float nq = fmaxf(sqrtf(S[d]),     1e-12f);
    const float nk = fmaxf(sqrtf(S[6 + e]), 1e-12f);
    attn[tid] = S[12 + tid] / (nq * nk) * SCALE;
  }
  __syncthreads();
  if (tid < 6) {                 // softmax over e for row d = tid
    float m = attn[tid * 6];
    for (int e = 1; e < 6; ++e) m = fmaxf(m, attn[tid * 6 + e]);
    float ex[6]; float sum = 0.0f;
    for (int e = 0; e < 6; ++e) { ex[e] = expf(attn[tid * 6 + e] - m); sum += ex[e]; }
    const float inv = 1.0f / sum;
    for (int e = 0; e < 6; ++e) attn[tid * 6 + e] = ex[e] * inv;
  }
  __syncthreads();
  for (int i = tid; i < 288; i += 64) {        // 48 rows x 6 cols of this head
    const int c = i / 6, e = i - 6 * (i / 6);
    float s = 0.0f;
#pragma unroll
    for (int d = 0; d < 6; ++d) s += wp[c * 48 + 6 * h + d] * attn[d * 6 + e];
    Mmat[((size_t)b * 48 + c) * 48 + 6 * h + e] = s;
  }
}

// ---------------------------------------------------------------------------
// K3: y[b][c][n] = sum_{c'} M_b[c][c'] * v[b][c'][n]   (M via scalar loads)
// ---------------------------------------------------------------------------
__global__ __launch_bounds__(256) void k3_out(
    const float* __restrict__ v_ws, const float* __restrict__ Mmat,
    float* __restrict__ y)
{
  const int b = blockIdx.x >> 8;
  const int n = ((blockIdx.x & 255) << 8) + threadIdx.x;
  const float* vb = v_ws + ((size_t)b * 48) * NPIX + n;
  const float* Mb = Mmat + (size_t)b * 2304;
  float vv[48];
#pragma unroll
  for (int c = 0; c < 48; ++c) vv[c] = vb[(size_t)c * NPIX];
  float* yb = y + ((size_t)b * 48) * NPIX + n;
#pragma unroll 4
  for (int c = 0; c < 48; ++c) {
    float s = 0.0f;
#pragma unroll
    for (int cc = 0; cc < 48; ++cc) s = fmaf(Mb[c * 48 + cc], vv[cc], s);
    yb[(size_t)c * NPIX] = s;
  }
}

extern "C" void kernel_launch(void* const* d_in, const int* in_sizes, int n_in,
                              void* d_out, int out_size, void* d_ws, size_t ws_size,
                              hipStream_t stream)
{
  const float* x  = (const float*)d_in[0];
  const float* w1 = (const float*)d_in[1];   // (144,48,1,1)
  const float* wd = (const float*)d_in[2];   // (144,1,3,3)
  const float* wp = (const float*)d_in[3];   // (48,48,1,1)
  float* ws = (float*)d_ws;
  float* v_ws      = ws + V_OFF;
  float* gram_part = ws + GP_OFF;
  float* Mmat      = ws + M_OFF;

  hipLaunchKernelGGL(k1_qkv, dim3(2048), dim3(T1), 0, stream,
                     x, w1, wd, v_ws, gram_part);
  hipLaunchKernelGGL(k2_attn, dim3(64), dim3(64), 0, stream,
                     gram_part, wp, Mmat);
  hipLaunchKernelGGL(k3_out, dim3(2048), dim3(256), 0, stream,
                     v_ws, Mmat, (float*)d_out);
}

// Round 2
// 699.141 us; speedup vs baseline: 2.2962x; 2.2962x over previous
//
#include <hip/hip_runtime.h>
#include <math.h>

#define SCALE 0.4082482904638631f   // 1/sqrt(6)

#define BATCH 8
#define CIN   48
#define HW    256
#define NPIX  65536

// ---------------- new-path workspace layout (float elements) ----------------
#define QKV_OFF  0
#define QKV_SIZE (BATCH*144*NPIX)          // 75,497,472 floats (~302 MB)
#define GP2_OFF  (QKV_OFF + QKV_SIZE)
#define GP2_SIZE (BATCH*64*8*48)           // per-tile gram partials
#define M2_OFF   (GP2_OFF + GP2_SIZE)
#define M2_SIZE  (BATCH*48*48)
#define WS_NEED  ((size_t)(QKV_SIZE + GP2_SIZE + M2_SIZE) * 4)

// ---------------- fallback (round-1) workspace layout ----------------
#define V_OFF   0
#define V_SIZE  (BATCH*48*NPIX)
#define GP_OFF  (V_OFF + V_SIZE)
#define GP_SIZE (2048*384)
#define M_OFF   (GP_OFF + GP_SIZE)

// ===========================================================================
// K_a: 1x1 conv (48 -> 144). One pixel per thread; x cached in 48 VGPRs;
// weights are wave-uniform -> pure s_load broadcast (no LDS, no vmem/ds mix).
// ===========================================================================
__global__ __launch_bounds__(256) void ka_conv1(
    const float* __restrict__ x, const float* __restrict__ w1,
    float* __restrict__ qkv)
{
  const int g = blockIdx.x * 256 + threadIdx.x;
  const int b = g >> 16;
  const int n = g & 65535;
  const float* xb = x + ((size_t)b * CIN) * NPIX + n;
  float xv[48];
#pragma unroll
  for (int ic = 0; ic < 48; ++ic) xv[ic] = xb[(size_t)ic * NPIX];
  float* ob = qkv + ((size_t)b * 144) * NPIX + n;
#pragma unroll 1
  for (int oc0 = 0; oc0 < 144; oc0 += 12) {
    float acc[12];
#pragma unroll
    for (int j = 0; j < 12; ++j) acc[j] = 0.0f;
#pragma unroll
    for (int ic = 0; ic < 48; ++ic) {
      const float xr = xv[ic];
#pragma unroll
      for (int j = 0; j < 12; ++j)
        acc[j] = fmaf(w1[(oc0 + j) * 48 + ic], xr, acc[j]);
    }
#pragma unroll
    for (int j = 0; j < 12; ++j) ob[(size_t)(oc0 + j) * NPIX] = acc[j];
  }
}

// ===========================================================================
// K_b: depthwise 3x3 on qkv_raw (global reads, L1/L2 absorb halo reuse).
// Block = 256 threads, tile 64x16 px (thread = 4x1 strip). Per head: dw for
// 12 q/k channels -> 48 gram partials -> LDS tree reduction -> per-tile
// partial. v channels dw'd and written straight to d_out.
// LDS: 256*52*4 = 53.2 KB -> 2 blocks/CU.
// ===========================================================================
__global__ __launch_bounds__(256) void kb_dw(
    const float* __restrict__ qkv, const float* __restrict__ wd,
    float* __restrict__ vout, float* __restrict__ gram_part)
{
  __shared__ float red[256 * 52];
  __shared__ float pr[192];

  const int blk = blockIdx.x;
  const int b   = blk >> 6;
  const int t   = blk & 63;
  const int tx  = t & 3, ty = t >> 2;
  const int tid = threadIdx.x;
  const int x0  = tx * 64 + (tid & 15) * 4;
  const int y   = ty * 16 + (tid >> 4);
  const bool xm = (x0 > 0), xp = (x0 < 252);
  const float* qb = qkv + ((size_t)b * 144) * NPIX;

  auto dwc = [&](int c, float* o) {
    const float* plane = qb + (size_t)c * NPIX;
    const float* w9 = wd + c * 9;
    float rr[3][6];
#pragma unroll
    for (int dr = 0; dr < 3; ++dr) {
      const int r = y - 1 + dr;
      if ((unsigned)r < 256u) {
        const float* rp = plane + r * 256 + x0;
        const float4 bv = *(const float4*)rp;
        rr[dr][1] = bv.x; rr[dr][2] = bv.y; rr[dr][3] = bv.z; rr[dr][4] = bv.w;
        rr[dr][0] = xm ? rp[-1] : 0.0f;
        rr[dr][5] = xp ? rp[4]  : 0.0f;
      } else {
#pragma unroll
        for (int j = 0; j < 6; ++j) rr[dr][j] = 0.0f;
      }
    }
#pragma unroll
    for (int p = 0; p < 4; ++p) {
      float s = 0.0f;
#pragma unroll
      for (int dr = 0; dr < 3; ++dr)
#pragma unroll
        for (int dx = 0; dx < 3; ++dx)
          s = fmaf(w9[dr * 3 + dx], rr[dr][p + dx], s);
      o[p] = s;
    }
  };

  for (int h = 0; h < 8; ++h) {
    float q[6][4], k[6][4];
#pragma unroll
    for (int j = 0; j < 6; ++j) dwc(6 * h + j, q[j]);
#pragma unroll
    for (int j = 0; j < 6; ++j) dwc(48 + 6 * h + j, k[j]);

    float g48[48];
#pragma unroll
    for (int d = 0; d < 6; ++d) {
      float s = 0.0f;
#pragma unroll
      for (int p = 0; p < 4; ++p) s = fmaf(q[d][p], q[d][p], s);
      g48[d] = s;
    }
#pragma unroll
    for (int e = 0; e < 6; ++e) {
      float s = 0.0f;
#pragma unroll
      for (int p = 0; p < 4; ++p) s = fmaf(k[e][p], k[e][p], s);
      g48[6 + e] = s;
    }
#pragma unroll
    for (int d = 0; d < 6; ++d)
#pragma unroll
      for (int e = 0; e < 6; ++e) {
        float s = 0.0f;
#pragma unroll
        for (int p = 0; p < 4; ++p) s = fmaf(q[d][p], k[e][p], s);
        g48[12 + 6 * d + e] = s;
      }

    float4* wrow = (float4*)(red + tid * 52);
#pragma unroll
    for (int j = 0; j < 12; ++j)
      wrow[j] = make_float4(g48[4 * j], g48[4 * j + 1], g48[4 * j + 2], g48[4 * j + 3]);
    __syncthreads();

    if (tid < 192) {
      const int vv = tid >> 2, ch = tid & 3;
      float s = 0.0f;
      const float* base = red + (ch * 64) * 52 + vv;
      for (int p = 0; p < 64; ++p) s += base[p * 52];
      pr[vv * 4 + ch] = s;
    }
    __syncthreads();
    if (tid < 48)
      gram_part[(((size_t)b * 64 + t) * 8 + h) * 48 + tid] =
          pr[tid * 4] + pr[tid * 4 + 1] + pr[tid * 4 + 2] + pr[tid * 4 + 3];
    __syncthreads();
  }

  // v channels -> d_out (coalesced float4)
#pragma unroll 1
  for (int c = 0; c < 48; ++c) {
    float o[4];
    dwc(96 + c, o);
    float4* vp = (float4*)(vout + ((size_t)b * 48 + c) * NPIX + y * 256 + x0);
    *vp = make_float4(o[0], o[1], o[2], o[3]);
  }
}

// ===========================================================================
// K_d: per (b,head): sum 64 tile partials -> norms -> softmax -> fold W_proj
// ===========================================================================
__global__ void kd_attn(const float* __restrict__ gram_part,
                        const float* __restrict__ wp, float* __restrict__ Mmat)
{
  const int b = blockIdx.x >> 3;
  const int h = blockIdx.x & 7;
  __shared__ float S[48];
  __shared__ float attn[36];
  const int tid = threadIdx.x;   // 64 threads

  if (tid < 48) {
    float s = 0.0f;
    for (int t = 0; t < 64; ++t)
      s += gram_part[(((size_t)b * 64 + t) * 8 + h) * 48 + tid];
    S[tid] = s;
  }
  __syncthreads();
  if (tid < 36) {
    const int d = tid / 6, e = tid - 6 * d;
    const float nq = fmaxf(sqrtf(S[d]),     1e-12f);
    const float nk = fmaxf(sqrtf(S[6 + e]), 1e-12f);
    attn[tid] = S[12 + tid] / (nq * nk) * SCALE;
  }
  __syncthreads();
  if (tid < 6) {
    float m = attn[tid * 6];
    for (int e = 1; e < 6; ++e) m = fmaxf(m, attn[tid * 6 + e]);
    float ex[6]; float sum = 0.0f;
    for (int e = 0; e < 6; ++e) { ex[e] = expf(attn[tid * 6 + e] - m); sum += ex[e]; }
    const float inv = 1.0f / sum;
    for (int e = 0; e < 6; ++e) attn[tid * 6 + e] = ex[e] * inv;
  }
  __syncthreads();
  for (int i = tid; i < 288; i += 64) {
    const int c = i / 6, e = i - 6 * (i / 6);
    float s = 0.0f;
#pragma unroll
    for (int d = 0; d < 6; ++d) s += wp[c * 48 + 6 * h + d] * attn[d * 6 + e];
    Mmat[((size_t)b * 48 + c) * 48 + 6 * h + e] = s;
  }
}

// ===========================================================================
// K_e: y[b][c][n] = sum_{c'} M_b[c][c'] * v[b][c'][n], in-place on d_out
// (each thread reads its 48 v values first, then overwrites the same column)
// ===========================================================================
__global__ __launch_bounds__(256) void ke_out(
    float* __restrict__ vy, const float* __restrict__ Mmat)
{
  const int b = blockIdx.x >> 8;
  const int n = ((blockIdx.x & 255) << 8) + threadIdx.x;
  float* vb = vy + ((size_t)b * 48) * NPIX + n;
  const float* Mb = Mmat + (size_t)b * 2304;
  float vv[48];
#pragma unroll
  for (int c = 0; c < 48; ++c) vv[c] = vb[(size_t)c * NPIX];
#pragma unroll 4
  for (int c = 0; c < 48; ++c) {
    float s = 0.0f;
#pragma unroll
    for (int cc = 0; cc < 48; ++cc) s = fmaf(Mb[c * 48 + cc], vv[cc], s);
    vb[(size_t)c * NPIX] = s;
  }
}

// ===========================================================================
// ================== fallback path (round-1, proven) ========================
// ===========================================================================
#define TILE  16
#define HALO  18
#define HP    324
#define T1    384

__global__ __launch_bounds__(T1, 3) void k1_qkv(
    const float* __restrict__ x, const float* __restrict__ w1,
    const float* __restrict__ wd, float* __restrict__ v_ws,
    float* __restrict__ gram_part)
{
  __shared__ float xs[CIN * HP];
  __shared__ __align__(16) float qh[HP * 12];
  __shared__ float pr[192];

  const int blk  = blockIdx.x;
  const int b    = blk >> 8;
  const int tile = blk & 255;
  const int ty0  = (tile >> 4) * TILE;
  const int tx0  = (tile & 15) * TILE;
  const int tid  = threadIdx.x;

  const float* xb = x + (size_t)b * CIN * NPIX;
  for (int e = tid; e < CIN * HP; e += T1) {
    const int ic = e / HP;
    const int hp = e - ic * HP;
    const int r  = hp / HALO;
    const int c  = hp - r * HALO;
    const int gy = ty0 - 1 + r;
    const int gx = tx0 - 1 + c;
    float v = 0.0f;
    if ((unsigned)gy < (unsigned)HW && (unsigned)gx < (unsigned)HW)
      v = xb[ic * NPIX + gy * HW + gx];
    xs[e] = v;
  }
  __syncthreads();

  const int px = tid & 15;
  const int py = tid >> 4;
  float* gp = gram_part + (size_t)blk * 384;

  for (int h = 0; h < 8; ++h) {
    if (tid < HP) {
      float acc[12];
#pragma unroll
      for (int j = 0; j < 12; ++j) acc[j] = 0.0f;
      const float* wq = w1 + (6 * h) * CIN;
      const float* wk = w1 + (48 + 6 * h) * CIN;
#pragma unroll
      for (int ic = 0; ic < CIN; ++ic) {
        const float xv = xs[ic * HP + tid];
#pragma unroll
        for (int j = 0; j < 6; ++j) {
          acc[j]     = fmaf(wq[j * CIN + ic], xv, acc[j]);
          acc[6 + j] = fmaf(wk[j * CIN + ic], xv, acc[6 + j]);
        }
      }
      float4* qp = (float4*)(qh + tid * 12);
      qp[0] = make_float4(acc[0], acc[1], acc[2],  acc[3]);
      qp[1] = make_float4(acc[4], acc[5], acc[6],  acc[7]);
      qp[2] = make_float4(acc[8], acc[9], acc[10], acc[11]);
    }
    __syncthreads();

    float val[12];
    if (tid < 256) {
#pragma unroll
      for (int j = 0; j < 12; ++j) val[j] = 0.0f;
#pragma unroll
      for (int t = 0; t < 9; ++t) {
        const int dy = t / 3, dx = t - 3 * (t / 3);
        const float* base = qh + ((py + dy) * HALO + (px + dx)) * 12;
        float f[12];
        *(float4*)(f + 0) = *(const float4*)(base + 0);
        *(float4*)(f + 4) = *(const float4*)(base + 4);
        *(float4*)(f + 8) = *(const float4*)(base + 8);
        float w_[12];
#pragma unroll
        for (int j = 0; j < 6; ++j) {
          w_[j]     = wd[(6 * h + j) * 9 + t];
          w_[6 + j] = wd[(48 + 6 * h + j) * 9 + t];
        }
#pragma unroll
        for (int j = 0; j < 12; ++j) val[j] = fmaf(w_[j], f[j], val[j]);
      }
    }
    __syncthreads();

    if (tid < 256) {
      float4* qp = (float4*)(qh + tid * 12);
      qp[0] = make_float4(val[0], val[1], val[2],  val[3]);
      qp[1] = make_float4(val[4], val[5], val[6],  val[7]);
      qp[2] = make_float4(val[8], val[9], val[10], val[11]);
    }
    __syncthreads();

    if (tid < 192) {
      const int vv = tid >> 2, ch = tid & 3;
      const float* base = qh + ch * 64 * 12;
      float s = 0.0f;
      if (vv < 12) {
        for (int p = 0; p < 64; ++p) {
          const float a = base[p * 12 + vv];
          s = fmaf(a, a, s);
        }
      } else {
        const int de = vv - 12;
        const int d = de / 6, e = de - 6 * (de / 6);
        for (int p = 0; p < 64; ++p)
          s = fmaf(base[p * 12 + d], base[p * 12 + 6 + e], s);
      }
      pr[vv * 4 + ch] = s;
    }
    __syncthreads();
    if (tid < 48)
      gp[h * 48 + tid] = pr[tid * 4] + pr[tid * 4 + 1] + pr[tid * 4 + 2] + pr[tid * 4 + 3];
    __syncthreads();
  }

  for (int g = 0; g < 6; ++g) {
    if (tid < HP) {
      float acc[8];
#pragma unroll
      for (int j = 0; j < 8; ++j) acc[j] = 0.0f;
      const float* wv = w1 + (96 + 8 * g) * CIN;
#pragma unroll
      for (int ic = 0; ic < CIN; ++ic) {
        const float xv = xs[ic * HP + tid];
#pragma unroll
        for (int j = 0; j < 8; ++j)
          acc[j] = fmaf(wv[j * CIN + ic], xv, acc[j]);
      }
      float4* qp = (float4*)(qh + tid * 12);
      qp[0] = make_float4(acc[0], acc[1], acc[2], acc[3]);
      qp[1] = make_float4(acc[4], acc[5], acc[6], acc[7]);
    }
    __syncthreads();

    if (tid < 256) {
      float val[8];
#pragma unroll
      for (int j = 0; j < 8; ++j) val[j] = 0.0f;
#pragma unroll
      for (int t = 0; t < 9; ++t) {
        const int dy = t / 3, dx = t - 3 * (t / 3);
        const float* base = qh + ((py + dy) * HALO + (px + dx)) * 12;
        float f[8];
        *(float4*)(f + 0) = *(const float4*)(base + 0);
        *(float4*)(f + 4) = *(const float4*)(base + 4);
        float w_[8];
#pragma unroll
        for (int j = 0; j < 8; ++j) w_[j] = wd[(96 + 8 * g + j) * 9 + t];
#pragma unroll
        for (int j = 0; j < 8; ++j) val[j] = fmaf(w_[j], f[j], val[j]);
      }
      const int gy = ty0 + py, gx = tx0 + px;
      float* vo = v_ws + (size_t)b * 48 * NPIX + gy * HW + gx;
#pragma unroll
      for (int j = 0; j < 8; ++j) vo[(size_t)(8 * g + j) * NPIX] = val[j];
    }
    __syncthreads();
  }
}

__global__ void k2_attn(const float* __restrict__ gram_part,
                        const float* __restrict__ wp, float* __restrict__ Mmat)
{
  const int b = blockIdx.x >> 3;
  const int h = blockIdx.x & 7;
  __shared__ float S[48];
  __shared__ float attn[36];
  const int tid = threadIdx.x;

  if (tid < 48) {
    const float* gpp = gram_part + (size_t)(b * 256) * 384 + h * 48 + tid;
    float s = 0.0f;
    for (int t = 0; t < 256; ++t) s += gpp[(size_t)t * 384];
    S[tid] = s;
  }
  __syncthreads();
  if (tid < 36) {
    const int d = tid / 6, e = tid - 6 * d;
    const float nq = fmaxf(sqrtf(S[d]),     1e-12f);
    const float nk = fmaxf(sqrtf(S[6 + e]), 1e-12f);
    attn[tid] = S[12 + tid] / (nq * nk) * SCALE;
  }
  __syncthreads();
  if (tid < 6) {
    float m = attn[tid * 6];
    for (int e = 1; e < 6; ++e) m = fmaxf(m, attn[tid * 6 + e]);
    float ex[6]; float sum = 0.0f;
    for (int e = 0; e < 6; ++e) { ex[e] = expf(attn[tid * 6 + e] - m); sum += ex[e]; }
    const float inv = 1.0f / sum;
    for (int e = 0; e < 6; ++e) attn[tid * 6 + e] = ex[e] * inv;
  }
  __syncthreads();
  for (int i = tid; i < 288; i += 64) {
    const int c = i / 6, e = i - 6 * (i / 6);
    float s = 0.0f;
#pragma unroll
    for (int d = 0; d < 6; ++d) s += wp[c * 48 + 6 * h + d] * attn[d * 6 + e];
    Mmat[((size_t)b * 48 + c) * 48 + 6 * h + e] = s;
  }
}

__global__ __launch_bounds__(256) void k3_out(
    const float* __restrict__ v_ws, const float* __restrict__ Mmat,
    float* __restrict__ y)
{
  const int b = blockIdx.x >> 8;
  const int n = ((blockIdx.x & 255) << 8) + threadIdx.x;
  const float* vb = v_ws + ((size_t)b * 48) * NPIX + n;
  const float* Mb = Mmat + (size_t)b * 2304;
  float vv[48];
#pragma unroll
  for (int c = 0; c < 48; ++c) vv[c] = vb[(size_t)c * NPIX];
  float* yb = y + ((size_t)b * 48) * NPIX + n;
#pragma unroll 4
  for (int c = 0; c < 48; ++c) {
    float s = 0.0f;
#pragma unroll
    for (int cc = 0; cc < 48; ++cc) s = fmaf(Mb[c * 48 + cc], vv[cc], s);
    yb[(size_t)c * NPIX] = s;
  }
}

// ===========================================================================
extern "C" void kernel_launch(void* const* d_in, const int* in_sizes, int n_in,
                              void* d_out, int out_size, void* d_ws, size_t ws_size,
                              hipStream_t stream)
{
  const float* x  = (const float*)d_in[0];
  const float* w1 = (const float*)d_in[1];   // (144,48,1,1)
  const float* wd = (const float*)d_in[2];   // (144,1,3,3)
  const float* wp = (const float*)d_in[3];   // (48,48,1,1)
  float* ws = (float*)d_ws;

  if (ws_size >= WS_NEED) {
    float* qkv  = ws + QKV_OFF;
    float* gp2  = ws + GP2_OFF;
    float* Mmat = ws + M2_OFF;
    hipLaunchKernelGGL(ka_conv1, dim3(2048), dim3(256), 0, stream, x, w1, qkv);
    hipLaunchKernelGGL(kb_dw,    dim3(512),  dim3(256), 0, stream, qkv, wd,
                       (float*)d_out, gp2);
    hipLaunchKernelGGL(kd_attn,  dim3(64),   dim3(64),  0, stream, gp2, wp, Mmat);
    hipLaunchKernelGGL(ke_out,   dim3(2048), dim3(256), 0, stream,
                       (float*)d_out, Mmat);
  } else {
    float* v_ws      = ws + V_OFF;
    float* gram_part = ws + GP_OFF;
    float* Mmat      = ws + M_OFF;
    hipLaunchKernelGGL(k1_qkv, dim3(2048), dim3(T1), 0, stream, x, w1, wd, v_ws, gram_part);
    hipLaunchKernelGGL(k2_attn, dim3(64), dim3(64), 0, stream, gram_part, wp, Mmat);
    hipLaunchKernelGGL(k3_out, dim3(2048), dim3(256), 0, stream, v_ws, Mmat, (float*)d_out);
  }
}